// Round 11
// baseline (2508.608 us; speedup 1.0000x reference)
//
#include <hip/hip_runtime.h>
#include <stdint.h>

// LSTMTimeDecoder on MI355X — round 11.
// Round 10 diagnosis: the slot is LDS-BW-bound (~200KB/slot through a
// 128 B/cy pipe: W_hh 128KB re-read every step + h 64KB + gbuf), plus 832
// cy/slot measured bank conflicts. This round cuts LDS bytes ~8x:
//  * W_hh -> REGISTERS via asm force-loads (asm outputs can't be
//    rematerialized — round 7/9's C++ loads were; round 10's asm lw proved
//    the mechanism). 128 VGPR/wave.
//  * Out-projection moved to a separate GEMM kernel k_out over an hs buffer
//    (134MB in ws, guarded): removes lw LDS reads + wave asymmetry; every
//    wave now issues EXACTLY 8 VMEM ops/slot -> uniform vmcnt(8) consume.
//  * h exchange buffer stored PRE-SWIZZLED in global (m173): producers store
//    at unit^(row&7); prefetch is a linear byte copy (reg-staged); hlds
//    scatter linear/conflict-free; gates ds_read applies the same XOR.
//  * Sentinel 3-slot sc0sc1 protocol byte-identical to rounds 6/10.

#define HD 512
#define BD 256
#define SD 512
#define OD 128
#define SENT 0xFF80FF80u

typedef __attribute__((ext_vector_type(8))) short short8;
typedef __attribute__((ext_vector_type(4))) float f32x4;
typedef __attribute__((ext_vector_type(4))) unsigned int u32x4;

static __device__ __forceinline__ unsigned short f2bf(float x) {
  unsigned int u = __float_as_uint(x);
  u += 0x7fffu + ((u >> 16) & 1u);
  return (unsigned short)(u >> 16);
}
static __device__ __forceinline__ float sigm(float x) {
  return 1.0f / (1.0f + __expf(-x));
}
static __device__ __forceinline__ float tanhf_(float x) {
  x = fminf(15.f, fmaxf(-15.f, x));
  float e = __expf(2.f * x);
  return (e - 1.f) / (e + 1.f);
}
static __device__ __forceinline__ int badchk(u32x4 v) {
  return (v.x == SENT) | (v.y == SENT) | (v.z == SENT) | (v.w == SENT);
}
#define KEEPALIVE(x) asm volatile("" : "+v"(x))

// ---------------- prep kernels ----------------
__global__ __launch_bounds__(256) void k_cvt(const float* __restrict__ whh,
                                             const float* __restrict__ linw,
                                             unsigned short* __restrict__ whhb,
                                             unsigned short* __restrict__ linwb) {
  int i = blockIdx.x * 256 + threadIdx.x;
  whhb[i] = f2bf(whh[i]);
  if (i < OD * HD) linwb[i] = f2bf(linw[i]);
}

__global__ __launch_bounds__(256) void k_td(const float* __restrict__ t,
                                            float* __restrict__ td) {
  int i = blockIdx.x * 256 + threadIdx.x;
  float v = 0.f;
  if (i >= BD) v = t[i] - t[i - BD];
  td[i] = v;
}

__global__ __launch_bounds__(256) void k_u(const float* __restrict__ wih,
                                           const float* __restrict__ tw,
                                           const float* __restrict__ tb,
                                           const float* __restrict__ bih,
                                           const float* __restrict__ bhh,
                                           float* __restrict__ u,
                                           float* __restrict__ ub) {
  int gc = blockIdx.x * 256 + threadIdx.x;
  const float4* w4 = (const float4*)(wih + (size_t)gc * (2 * HD) + HD);
  const float4* t4 = (const float4*)tw;
  const float4* b4 = (const float4*)tb;
  float a = 0.f, b = 0.f;
  for (int k = 0; k < HD / 4; ++k) {
    float4 w = w4[k], tv = t4[k], bv = b4[k];
    a += w.x * tv.x + w.y * tv.y + w.z * tv.z + w.w * tv.w;
    b += w.x * bv.x + w.y * bv.y + w.z * bv.z + w.w * bv.w;
  }
  u[gc] = a;
  ub[gc] = b + bih[gc] + bhh[gc];
}

__global__ __launch_bounds__(1024) void k_cw(const float* __restrict__ C,
                                             const float* __restrict__ wih,
                                             const float* __restrict__ ub,
                                             float* __restrict__ CW) {
  int gc = blockIdx.x * 64 + (threadIdx.x & 63);
  int b  = blockIdx.y * 16 + (threadIdx.x >> 6);
  const float4* c4 = (const float4*)(C + (size_t)b * HD);
  const float4* w4 = (const float4*)(wih + (size_t)gc * (2 * HD));
  float acc = 0.f;
  for (int k = 0; k < HD / 4; ++k) {
    float4 cv = c4[k], wv = w4[k];
    acc += cv.x * wv.x + cv.y * wv.y + cv.z * wv.z + cv.w * wv.w;
  }
  CW[(size_t)b * (4 * HD) + gc] = acc + ub[gc];
}

__global__ __launch_bounds__(256) void k_poison(unsigned int* __restrict__ hbuf) {
  u32x4 s = {SENT, SENT, SENT, SENT};
  unsigned int* p = hbuf + (size_t)(blockIdx.x * 256 + threadIdx.x) * 4;
  asm volatile("global_store_dwordx4 %0, %1, off sc0 sc1" :: "v"(p), "v"(s) : "memory");
}

// ---------------- main recurrent kernel ----------------
__global__ __launch_bounds__(256, 1) void k_main(
    const float* __restrict__ CW, const float* __restrict__ u,
    const float* __restrict__ td, const unsigned short* __restrict__ whhb,
    unsigned short* __restrict__ hbuf, unsigned short* __restrict__ hs)
{
  __shared__ __align__(16) unsigned short hlds[16 * HD];  // 16KB (swizzled image)
  __shared__ float gbuf[4][16][33];

  const int tid  = threadIdx.x;
  const int lane = tid & 63;
  const int wv   = tid >> 6;          // wave == gate i,f,g,o
  const int m    = blockIdx.x & 15;   // member: h-cols [m*32, m*32+32)
  const int q    = blockIdx.x >> 4;   // 0..7
  const int g0   = q, g1 = q + 8;

  // ---- W_hh fragments -> REGISTERS via asm (pinned; cannot rematerialize) ----
  short8 w0[16], w1[16];
  {
    const unsigned short* wb =
        whhb + ((size_t)wv * HD + m * 32 + (lane & 15)) * HD + (lane >> 4) * 8;
    #pragma unroll
    for (int kk = 0; kk < 16; ++kk) {
      asm volatile("global_load_dwordx4 %0, %2, off\n\t"
                   "global_load_dwordx4 %1, %3, off"
                   : "=&v"(w0[kk]), "=&v"(w1[kk])
                   : "v"(wb + kk * 32), "v"(wb + 16 * HD + kk * 32) : "memory");
    }
  }

  // ---- per-thread cell constants ----
  const int r    = tid >> 4;
  const int jl0  = (tid & 15) * 2;
  const int grow0 = g0 * 16 + r;
  const int grow1 = g1 * 16 + r;
  float cwr0[8], cwr1[8], ur[8];
  #pragma unroll
  for (int g = 0; g < 4; ++g) {
    int col = g * HD + m * 32 + jl0;
    cwr0[g * 2]     = CW[(size_t)grow0 * (4 * HD) + col];
    cwr0[g * 2 + 1] = CW[(size_t)grow0 * (4 * HD) + col + 1];
    cwr1[g * 2]     = CW[(size_t)grow1 * (4 * HD) + col];
    cwr1[g * 2 + 1] = CW[(size_t)grow1 * (4 * HD) + col + 1];
    ur[g * 2]       = u[col];
    ur[g * 2 + 1]   = u[col + 1];
  }
  float c00 = 0.f, c01 = 0.f, c10 = 0.f, c11 = 0.f;

  char* hb0 = (char*)hbuf + (size_t)g0 * 49152;   // 3 slots x 16KB
  char* hb1 = (char*)hbuf + (size_t)g1 * 49152;

  // F-store byte offset within a slot (pre-swizzled layout: unit ^= row&7)
  const int col0 = m * 32 + jl0;
  const int foff = r * 1024 + (((col0 >> 3) ^ (r & 7)) << 4) + ((col0 * 2) & 15);
  // gates frag-read components
  const int arow  = lane & 15;
  const int akoff = lane >> 4;
  const int axor  = arow & 7;

  u32x4 vpA0, vpA1, vpA2, vpA3;   // in-flight h prefetch, group g0
  u32x4 vpB0, vpB1, vpB2, vpB3;   // group g1
  float tdnA = 0.f, tdnB = 0.f;   // in-flight td prefetch

  #pragma unroll
  for (int i = 0; i < 8; ++i) { KEEPALIVE(cwr0[i]); KEEPALIVE(cwr1[i]); KEEPALIVE(ur[i]); }
  asm volatile("s_waitcnt vmcnt(0)" ::: "memory");   // W frags + prep loads done
  __builtin_amdgcn_sched_barrier(0);
  __syncthreads();

  // ---- one slot: 8 VMEM ops (B,F,F2,C4,td) -> uniform vmcnt(8) consume ----
  auto slot = [&](int t, char* hbg, int growg, const float* cwrg,
                  float& c0R, float& c1R,
                  u32x4& v0, u32x4& v1, u32x4& v2, u32x4& v3, float& tdn) {
    const size_t oC = (size_t)(t % 3) * 16384;
    const size_t oN = (size_t)((t + 1) % 3) * 16384;
    const size_t oR = (size_t)((t + 2) % 3) * 16384;
    float tdv = 0.f;

    if (t > 0) {
      // consume h_t: uniform counted wait (my prev C5 is 8 ops deep)
      asm volatile("s_waitcnt vmcnt(8)" ::: "memory");
      __builtin_amdgcn_sched_barrier(0);
      tdv = tdn;
      int p0 = badchk(v0), p1 = badchk(v1), p2 = badchk(v2), p3 = badchk(v3);
      if (p0 | p1 | p2 | p3) {               // rare: prefetch raced peers' stores
        const char* src = hbg + oC + (size_t)tid * 16;
        int guard = 0;
        do {
          if (++guard > (1 << 16)) break;
          __builtin_amdgcn_s_sleep(1);
          if (p0) asm volatile("global_load_dwordx4 %0, %1, off sc0 sc1" : "=&v"(v0) : "v"(src) : "memory");
          if (p1) asm volatile("global_load_dwordx4 %0, %1, off sc0 sc1" : "=&v"(v1) : "v"(src + 4096) : "memory");
          if (p2) asm volatile("global_load_dwordx4 %0, %1, off sc0 sc1" : "=&v"(v2) : "v"(src + 8192) : "memory");
          if (p3) asm volatile("global_load_dwordx4 %0, %1, off sc0 sc1" : "=&v"(v3) : "v"(src + 12288) : "memory");
          asm volatile("s_waitcnt vmcnt(0)" ::: "memory");   // over-drain: safe
          __builtin_amdgcn_sched_barrier(0);
          p0 = badchk(v0); p1 = badchk(v1); p2 = badchk(v2); p3 = badchk(v3);
        } while (p0 | p1 | p2 | p3);
      }
      // linear scatter of the swizzled image (conflict-free)
      *(u32x4*)((char*)hlds + (size_t)tid * 16)         = v0;
      *(u32x4*)((char*)hlds + 4096 + (size_t)tid * 16)  = v1;
      *(u32x4*)((char*)hlds + 8192 + (size_t)tid * 16)  = v2;
      *(u32x4*)((char*)hlds + 12288 + (size_t)tid * 16) = v3;
    }
    asm volatile("s_waitcnt lgkmcnt(0)" ::: "memory");
    __builtin_amdgcn_s_barrier();            // A: hlds ready

    // ---- gates = h_t @ W^T : A from hlds (XOR addr), B = registers ----
    f32x4 acc0 = {0.f, 0.f, 0.f, 0.f}, acc1 = {0.f, 0.f, 0.f, 0.f};
    if (t > 0) {
      #pragma unroll
      for (int kk = 0; kk < 16; ++kk) {
        short8 a = *(const short8*)((const char*)hlds + (size_t)arow * 1024 +
                                    (size_t)(((kk * 4 + akoff) ^ axor) << 4));
        acc0 = __builtin_amdgcn_mfma_f32_16x16x32_bf16(a, w0[kk], acc0, 0, 0, 0);
        acc1 = __builtin_amdgcn_mfma_f32_16x16x32_bf16(a, w1[kk], acc1, 0, 0, 0);
      }
    }
    {
      int rr = (lane >> 4) * 4, cc = lane & 15;
      #pragma unroll
      for (int qq = 0; qq < 4; ++qq) {
        gbuf[wv][rr + qq][cc]      = acc0[qq];
        gbuf[wv][rr + qq][16 + cc] = acc1[qq];
      }
    }
    asm volatile("s_waitcnt lgkmcnt(0)" ::: "memory");
    __builtin_amdgcn_s_barrier();            // B: gbuf ready

    // ---- cell (2 elems/thread) ----
    unsigned int hp;
    {
      float p0i = gbuf[0][r][jl0]     + cwrg[0] + tdv * ur[0];
      float p1i = gbuf[0][r][jl0 + 1] + cwrg[1] + tdv * ur[1];
      float p0f = gbuf[1][r][jl0]     + cwrg[2] + tdv * ur[2];
      float p1f = gbuf[1][r][jl0 + 1] + cwrg[3] + tdv * ur[3];
      float p0g = gbuf[2][r][jl0]     + cwrg[4] + tdv * ur[4];
      float p1g = gbuf[2][r][jl0 + 1] + cwrg[5] + tdv * ur[5];
      float p0o = gbuf[3][r][jl0]     + cwrg[6] + tdv * ur[6];
      float p1o = gbuf[3][r][jl0 + 1] + cwrg[7] + tdv * ur[7];
      c0R = sigm(p0f) * c0R + sigm(p0i) * tanhf_(p0g);
      c1R = sigm(p1f) * c1R + sigm(p1i) * tanhf_(p1g);
      float h0 = sigm(p0o) * tanhf_(c0R);
      float h1 = sigm(p1o) * tanhf_(c1R);
      hp = (unsigned int)f2bf(h0) | ((unsigned int)f2bf(h1) << 16);
    }

    // ---- fixed VMEM tail: B, F, F2, C4, td (8 ops) ----
    {  // B: repoison slot (t+2)%3, member's phys KB (ordered before next F by
       //    the next consume's vmcnt(8), which retires it)
      char* pp = hbg + oR + (size_t)m * 1024 + (size_t)tid * 4;
      unsigned int s = SENT;
      asm volatile("global_store_dword %0, %1, off sc0 sc1" :: "v"(pp), "v"(s) : "memory");
    }
    {  // F: h_{t+1} exchange store (swizzled offset)
      char* hsl = hbg + oN + foff;
      asm volatile("global_store_dword %0, %1, off sc0 sc1" :: "v"(hsl), "v"(hp) : "memory");
    }
    {  // F2: hs row for k_out (plain, fire-and-forget)
      unsigned short* hd = hs + ((size_t)t * BD + growg) * HD + col0;
      asm volatile("global_store_dword %0, %1, off" :: "v"(hd), "v"(hp) : "memory");
    }
    {  // C: prefetch h_{t+1} (linear copy of swizzled image) + next td
      const char* src = hbg + oN + (size_t)tid * 16;
      asm volatile(
          "global_load_dwordx4 %0, %4, off sc0 sc1\n\t"
          "global_load_dwordx4 %1, %5, off sc0 sc1\n\t"
          "global_load_dwordx4 %2, %6, off sc0 sc1\n\t"
          "global_load_dwordx4 %3, %7, off sc0 sc1"
          : "=&v"(v0), "=&v"(v1), "=&v"(v2), "=&v"(v3)
          : "v"(src), "v"(src + 4096), "v"(src + 8192), "v"(src + 12288)
          : "memory");
      int tt = (t + 1 < SD) ? (t + 1) : t;
      const float* ta = td + (size_t)tt * BD + growg;
      asm volatile("global_load_dword %0, %1, off" : "=&v"(tdn) : "v"(ta) : "memory");
    }
  };

  for (int t = 0; t < SD; ++t) {
    slot(t, hb0, grow0, cwr0, c00, c01, vpA0, vpA1, vpA2, vpA3, tdnA);
    slot(t, hb1, grow1, cwr1, c10, c11, vpB0, vpB1, vpB2, vpB3, tdnB);
  }
}

// ---------------- output projection: out = hs @ linW^T + lb ----------------
__global__ __launch_bounds__(256) void k_out(const unsigned short* __restrict__ hs,
                                             const unsigned short* __restrict__ linwb,
                                             const float* __restrict__ linb,
                                             float* __restrict__ out) {
  const int tid  = threadIdx.x;
  const int lane = tid & 63;
  const int w    = tid >> 6;
  const size_t R0 = (size_t)blockIdx.x * 64 + (size_t)w * 16;

  short8 a[16];
  {
    const unsigned short* ab = hs + (R0 + (lane & 15)) * HD + (lane >> 4) * 8;
    #pragma unroll
    for (int kk = 0; kk < 16; ++kk) a[kk] = *(const short8*)(ab + kk * 32);
  }

  f32x4 acc[8];
  #pragma unroll
  for (int j = 0; j < 8; ++j) acc[j] = (f32x4){0.f, 0.f, 0.f, 0.f};

  #pragma unroll 4
  for (int kk = 0; kk < 16; ++kk) {
    #pragma unroll
    for (int j = 0; j < 8; ++j) {
      const unsigned short* bb =
          linwb + (size_t)(j * 16 + (lane & 15)) * HD + kk * 32 + (lane >> 4) * 8;
      short8 b = *(const short8*)bb;
      acc[j] = __builtin_amdgcn_mfma_f32_16x16x32_bf16(a[kk], b, acc[j], 0, 0, 0);
    }
  }

  const int rr = (lane >> 4) * 4, cc = lane & 15;
  #pragma unroll
  for (int j = 0; j < 8; ++j) {
    float lb = linb[j * 16 + cc];
    #pragma unroll
    for (int qq = 0; qq < 4; ++qq)
      out[(R0 + rr + qq) * OD + j * 16 + cc] = acc[j][qq] + lb;
  }
}

// ---------------- launcher ----------------
extern "C" void kernel_launch(void* const* d_in, const int* in_sizes, int n_in,
                              void* d_out, int out_size, void* d_ws, size_t ws_size,
                              hipStream_t stream) {
  const float* C    = (const float*)d_in[0];
  const float* t    = (const float*)d_in[1];
  // d_in[2] = mask (unused by reference)
  const float* Wih  = (const float*)d_in[3];
  const float* Whh  = (const float*)d_in[4];
  const float* bih  = (const float*)d_in[5];
  const float* bhh  = (const float*)d_in[6];
  const float* linW = (const float*)d_in[7];
  const float* linb = (const float*)d_in[8];
  const float* tW   = (const float*)d_in[9];
  const float* tb   = (const float*)d_in[10];
  float* out = (float*)d_out;

  char* ws = (char*)d_ws;
  float*          CW    = (float*)(ws + 0);                 // 2,097,152
  float*          u     = (float*)(ws + 2097152);           // 8,192
  float*          ub    = (float*)(ws + 2105344);           // 8,192
  float*          td    = (float*)(ws + 2113536);           // 524,288
  unsigned short* whhb  = (unsigned short*)(ws + 2637824);  // 2,097,152
  unsigned short* linwb = (unsigned short*)(ws + 4734976);  // 131,072
  unsigned short* hbuf  = (unsigned short*)(ws + 4866048);  // 786,432
  unsigned short* hs    = (unsigned short*)(ws + 5652480);  // 512*256*512*2 = 134,217,728
  if (ws_size < 5652480ull + 134217728ull) return;  // clean fail: learn ws budget

  k_poison<<<192, 256, 0, stream>>>((unsigned int*)hbuf);
  k_cvt<<<4096, 256, 0, stream>>>(Whh, linW, whhb, linwb);
  k_td <<<512, 256, 0, stream>>>(t, td);
  k_u  <<<8, 256, 0, stream>>>(Wih, tW, tb, bih, bhh, u, ub);
  k_cw <<<dim3(32, 16), 1024, 0, stream>>>(C, Wih, ub, CW);
  k_main<<<128, 256, 0, stream>>>(CW, u, td, whhb, hbuf, hs);
  k_out<<<2048, 256, 0, stream>>>(hs, linwb, linb, out);
}